// Round 3
// baseline (112.533 us; speedup 1.0000x reference)
//
#include <hip/hip_runtime.h>

// Problem constants (from reference): B=16384, D=255, K=4, L=16, T=1020
constexpr int T_TUN = 1020;
constexpr int D_DST = 255;
constexpr int L_LNK = 16;
constexpr float EPS = 1e-8f;
constexpr int ROWS_PER_BLOCK = 16;  // 4 waves x 4 rows (concurrent, separate LDS regions)

__device__ __forceinline__ float read_lane_f(float v, int l) {
  return __builtin_bit_cast(float,
      __builtin_amdgcn_readlane(__builtin_bit_cast(int, v), l));
}

__global__ __launch_bounds__(256) void rowloss_kernel(
    const float* __restrict__ pred,     // [B, T]
    const float* __restrict__ demands,  // [B, D]
    const float* __restrict__ cur,      // [B, L]
    const float* __restrict__ caps,     // [L]
    const int*   __restrict__ t2l,      // [T]
    float* __restrict__ partials)       // [gridDim.x]
{
  const int tid  = threadIdx.x;
  const int lane = tid & 63;
  const int w    = tid >> 6;   // wave id 0..3

  // Bin-major per-lane bins: priv[link*64 + lane].
  //  - plain b32 RMW scatter (NOT ds atomics: measured 4x slower in R1)
  //  - FOUR regions per wave (one per row): 4 independent depth-16 may-alias
  //    RMW chains interleaved -> chain latency amortized over 4 rows
  //    (R2 with 2 chains beat 1 chain; this doubles concurrency again)
  //  - column reduce: lane's 16 copies are CONSECUTIVE -> ds_read_b128
  // LDS: 4 waves x 4 rows x 4KB = 64KB/block -> 2 blocks/CU (8 waves/CU),
  // still enough up-front global MLP to cover the HBM/L3 stream.
  __shared__ float priv_all[4][4][L_LNK * 64];
  __shared__ float wacc[4];

  const int b16 = lane & 15;       // this lane's bin for the reduce/stats
  const int g   = lane >> 4;       // lane group 0..3
  const float capinv = 1.0f / (caps[b16] + EPS);

  // Row-invariant scatter offsets: element index = link*64 + lane
  int off[4][4];
  bool dv[4];
#pragma unroll
  for (int j = 0; j < 4; ++j) {
    const int d = lane + 64 * j;
    dv[j] = (d < D_DST);
    const int dd = dv[j] ? d : 0;
    const int4 lk = ((const int4*)t2l)[dd];   // t2l[4d..4d+3]
    off[j][0] = lk.x * 64 + lane;
    off[j][1] = lk.y * 64 + lane;
    off[j][2] = lk.z * 64 + lane;
    off[j][3] = lk.w * 64 + lane;
  }

  const int row0 = blockIdx.x * ROWS_PER_BLOCK + w * 4;

  // ---- issue ALL global loads for all 4 rows up front (max MLP) ----
  float4 r4[4][4];
  float  dm[4][4];
  float  mycur[4];
#pragma unroll
  for (int r = 0; r < 4; ++r) {
    const int b = row0 + r;
    const float4* prow = (const float4*)(pred + (size_t)b * T_TUN);
    const float*  drow = demands + (size_t)b * D_DST;
    mycur[r] = cur[(size_t)b * L_LNK + b16];
#pragma unroll
    for (int j = 0; j < 4; ++j) {
      const int d = lane + 64 * j;
      if (dv[j]) { r4[r][j] = prow[d]; dm[r][j] = drow[d]; }
    }
  }

  // zero all 4 regions: 16x ds_write_b128
  {
    const float4 z = make_float4(0.f, 0.f, 0.f, 0.f);
#pragma unroll
    for (int r = 0; r < 4; ++r) {
      float4* pz = (float4*)priv_all[w][r];
#pragma unroll
      for (int i = 0; i < 4; ++i) pz[lane + 64 * i] = z;
    }
  }

  __builtin_amdgcn_wave_barrier();  // zeroes ordered before scatter (DS pipe in-order)

  // scatter: four independent may-alias RMW chains (one per row/region),
  // interleaved at the innermost level so their latencies overlap
  {
    float* p0 = priv_all[w][0];
    float* p1 = priv_all[w][1];
    float* p2 = priv_all[w][2];
    float* p3 = priv_all[w][3];
#pragma unroll
    for (int j = 0; j < 4; ++j) {
      if (!dv[j]) continue;            // only lane63/j3 diverges
      const float4 v0 = r4[0][j]; const float d0 = dm[0][j];
      const float4 v1 = r4[1][j]; const float d1 = dm[1][j];
      const float4 v2 = r4[2][j]; const float d2 = dm[2][j];
      const float4 v3 = r4[3][j]; const float d3 = dm[3][j];
      p0[off[j][0]] += v0.x * d0;
      p1[off[j][0]] += v1.x * d1;
      p2[off[j][0]] += v2.x * d2;
      p3[off[j][0]] += v3.x * d3;
      p0[off[j][1]] += v0.y * d0;
      p1[off[j][1]] += v1.y * d1;
      p2[off[j][1]] += v2.y * d2;
      p3[off[j][1]] += v3.y * d3;
      p0[off[j][2]] += v0.z * d0;
      p1[off[j][2]] += v1.z * d1;
      p2[off[j][2]] += v2.z * d2;
      p3[off[j][2]] += v3.z * d3;
      p0[off[j][3]] += v0.w * d0;
      p1[off[j][3]] += v1.w * d1;
      p2[off[j][3]] += v2.w * d2;
      p3[off[j][3]] += v3.w * d3;
    }
  }

  __builtin_amdgcn_wave_barrier();  // scatter ordered before reduce reads

  // column reduce all 4 rows: lane's 16 copies (16g..16g+15 of bin b16)
  float cs[4] = {0.f, 0.f, 0.f, 0.f};
#pragma unroll
  for (int r = 0; r < 4; ++r) {
    const float4* pr = (const float4*)(priv_all[w][r] + b16 * 64 + 16 * g);
#pragma unroll
    for (int q = 0; q < 4; ++q) {
      const float4 a = pr[q];
      cs[r] += a.x + a.y + a.z + a.w;
    }
  }
#pragma unroll
  for (int r = 0; r < 4; ++r) {
    cs[r] += __shfl_xor(cs[r], 16, 64);
    cs[r] += __shfl_xor(cs[r], 32, 64);
  }

  // fused stats per row: group 0 sums u, 1 sums u^2, 2 sums u*cur, 3 maxes u
  float val[4];
#pragma unroll
  for (int r = 0; r < 4; ++r) {
    const float u = cs[r] * capinv;
    val[r] = (g == 0) ? u : (g == 1) ? (u * u)
           : (g == 2) ? (u * mycur[r]) : u;
  }
#pragma unroll
  for (int m = 1; m < 16; m <<= 1) {
#pragma unroll
    for (int r = 0; r < 4; ++r) {
      const float o  = __shfl_xor(val[r], m, 64);
      const float sm = val[r] + o;
      const float mm = fmaxf(val[r], o);
      val[r] = (g == 3) ? mm : sm;
    }
  }
  float acc = 0.0f;
#pragma unroll
  for (int r = 0; r < 4; ++r) {
    const float s1 = read_lane_f(val[r], 0);
    const float s2 = read_lane_f(val[r], 16);
    const float s3 = read_lane_f(val[r], 32);
    const float mx = read_lane_f(val[r], 48);
    const float var = (s2 - s1 * s1 * (1.0f / 16.0f)) * (1.0f / 15.0f); // ddof=1
    acc += 0.3f * var + 0.5f * s3 + 0.2f * mx;
  }

  if (lane == 0) wacc[w] = acc;
  __syncthreads();
  if (tid == 0) partials[blockIdx.x] = wacc[0] + wacc[1] + wacc[2] + wacc[3];
}

__global__ __launch_bounds__(256) void reduce_kernel(
    const float* __restrict__ partials, int n, float* __restrict__ out, float invB)
{
  __shared__ float s[256];
  const int tid = threadIdx.x;
  const float4* p4 = (const float4*)partials;
  const int n4 = n >> 2;
  float a = 0.0f;
  for (int i = tid; i < n4; i += 256) {
    const float4 v = p4[i];
    a += v.x + v.y + v.z + v.w;
  }
  s[tid] = a;
  __syncthreads();
  for (int st = 128; st > 0; st >>= 1) {
    if (tid < st) s[tid] += s[tid + st];
    __syncthreads();
  }
  if (tid == 0) out[0] = s[0] * invB;
}

extern "C" void kernel_launch(void* const* d_in, const int* in_sizes, int n_in,
                              void* d_out, int out_size, void* d_ws, size_t ws_size,
                              hipStream_t stream) {
  const float* pred    = (const float*)d_in[0];  // [B, T]
  const float* demands = (const float*)d_in[1];  // [B, D]
  const float* cur     = (const float*)d_in[2];  // [B, L]
  const float* caps    = (const float*)d_in[3];  // [L]
  const int*   t2l     = (const int*)d_in[4];    // [T]
  float* out = (float*)d_out;

  const int L = in_sizes[3];          // 16
  const int B = in_sizes[2] / L;      // 16384

  const int grid = B / ROWS_PER_BLOCK;  // 1024
  float* partials = (float*)d_ws;       // grid floats

  rowloss_kernel<<<grid, 256, 0, stream>>>(pred, demands, cur, caps, t2l, partials);
  reduce_kernel<<<1, 256, 0, stream>>>(partials, grid, out, 1.0f / (float)B);
}

// Round 4
// 109.331 us; speedup vs baseline: 1.0293x; 1.0293x over previous
//
#include <hip/hip_runtime.h>

// Problem constants (from reference): B=16384, D=255, K=4, L=16, T=1020
constexpr int T_TUN = 1020;
constexpr int D_DST = 255;
constexpr int L_LNK = 16;
constexpr float EPS = 1e-8f;

// Persistent-ish grid: 512 blocks = 2 blocks/CU (LDS 32KB/block), each block
// loops NITER times over 8 rows (4 waves x 2 rows) with register
// double-buffered global loads -> HBM hides under the DS phase.
constexpr int GRID_BLOCKS = 512;
constexpr int ROWS_PER_ITER = 8;        // 4 waves x 2 rows
constexpr int NITER = 16384 / (GRID_BLOCKS * ROWS_PER_ITER);  // 4

__device__ __forceinline__ float read_lane_f(float v, int l) {
  return __builtin_bit_cast(float,
      __builtin_amdgcn_readlane(__builtin_bit_cast(int, v), l));
}

__global__ __launch_bounds__(256) void rowloss_kernel(
    const float* __restrict__ pred,     // [B, T]
    const float* __restrict__ demands,  // [B, D]
    const float* __restrict__ cur,      // [B, L]
    const float* __restrict__ caps,     // [L]
    const int*   __restrict__ t2l,      // [T]
    float* __restrict__ partials)       // [gridDim.x]
{
  const int tid  = threadIdx.x;
  const int lane = tid & 63;
  const int w    = tid >> 6;   // wave id 0..3

  // float2-packed bins: pb[link*64 + lane] = (rowA_acc, rowB_acc).
  //  - one b64 RMW per scatter step carries BOTH rows (halves scatter instrs)
  //  - bank(dword) = (2*lane)%32 -> 4 accesses/bank for b64 = ideal
  //  - plain RMW, NOT ds atomics (R1: atomics 4x slower)
  __shared__ float2 bins_all[4][L_LNK * 64];   // 8 KB/wave, 32 KB/block
  __shared__ float wacc[4];
  float2* pb = bins_all[w];

  const int b16 = lane & 15;       // this lane's bin for the reduce/stats
  const int g   = lane >> 4;       // lane group 0..3
  const float capinv = 1.0f / (caps[b16] + EPS);

  // Row-invariant scatter offsets: float2 index = link*64 + lane
  int off[4][4];
  bool dv[4];
#pragma unroll
  for (int j = 0; j < 4; ++j) {
    const int d = lane + 64 * j;
    dv[j] = (d < D_DST);
    const int dd = dv[j] ? d : 0;
    const int4 lk = ((const int4*)t2l)[dd];   // t2l[4d..4d+3]
    off[j][0] = lk.x * 64 + lane;
    off[j][1] = lk.y * 64 + lane;
    off[j][2] = lk.z * 64 + lane;
    off[j][3] = lk.w * 64 + lane;
  }

  const int rowbase = blockIdx.x * (NITER * ROWS_PER_ITER) + w * 2;

  // Double-buffered per-pair row data (registers)
  float4 r4[2][2][4];
  float  dm[2][2][4];
  float  cur2[2][2];

  // Issue the global loads for iteration t into buffer `buf`.
  auto loadp = [&](int t, int buf) {
#pragma unroll
    for (int r = 0; r < 2; ++r) {
      const int b = rowbase + t * ROWS_PER_ITER + r;
      const float4* prow = (const float4*)(pred + (size_t)b * T_TUN);
      const float*  drow = demands + (size_t)b * D_DST;
      cur2[buf][r] = cur[(size_t)b * L_LNK + b16];
#pragma unroll
      for (int j = 0; j < 4; ++j) {
        const int d = lane + 64 * j;
        if (dv[j]) { r4[buf][r][j] = prow[d]; dm[buf][r][j] = drow[d]; }
      }
    }
  };

  loadp(0, 0);

  float acc = 0.0f;

#pragma unroll
  for (int t = 0; t < NITER; ++t) {
    const int buf = t & 1;
    // prefetch next pair BEFORE consuming this one: HBM hides under DS phase
    if (t + 1 < NITER) loadp(t + 1, buf ^ 1);

    __builtin_amdgcn_wave_barrier();  // prior reduce reads before re-zero

    // zero the 8KB float2 region: 8x ds_write_b128
    {
      const float4 z = make_float4(0.f, 0.f, 0.f, 0.f);
      float4* pz = (float4*)pb;
#pragma unroll
      for (int i = 0; i < 8; ++i) pz[lane + 64 * i] = z;
    }

    __builtin_amdgcn_wave_barrier();  // zeroes before scatter (DS pipe in-order)

    // scatter: 16 b64 RMW steps, each carrying BOTH rows of the pair
#pragma unroll
    for (int j = 0; j < 4; ++j) {
      if (!dv[j]) continue;            // only lane63/j3 diverges
      const float4 vA = r4[buf][0][j]; const float dA = dm[buf][0][j];
      const float4 vB = r4[buf][1][j]; const float dB = dm[buf][1][j];
      { const int o = off[j][0]; float2 s = pb[o];
        s.x = fmaf(vA.x, dA, s.x); s.y = fmaf(vB.x, dB, s.y); pb[o] = s; }
      { const int o = off[j][1]; float2 s = pb[o];
        s.x = fmaf(vA.y, dA, s.x); s.y = fmaf(vB.y, dB, s.y); pb[o] = s; }
      { const int o = off[j][2]; float2 s = pb[o];
        s.x = fmaf(vA.z, dA, s.x); s.y = fmaf(vB.z, dB, s.y); pb[o] = s; }
      { const int o = off[j][3]; float2 s = pb[o];
        s.x = fmaf(vA.w, dA, s.x); s.y = fmaf(vB.w, dB, s.y); pb[o] = s; }
    }

    __builtin_amdgcn_wave_barrier();  // scatter before reduce reads

    // column reduce, bank-conflict-free via b16-rotated slot order:
    // slot s reads copies (16g+2s, 16g+2s+1) of bin b16 as (A,B,A,B).
    // dword-bank = 4*((jj+b16)&7) -> 16 b16-groups spread over all banks.
    float csA = 0.0f, csB = 0.0f;
    {
      const float4* pr = (const float4*)(pb + b16 * 64 + 16 * g);
#pragma unroll
      for (int jj = 0; jj < 8; ++jj) {
        const float4 v = pr[(jj + b16) & 7];
        csA += v.x + v.z;
        csB += v.y + v.w;
      }
    }
    csA += __shfl_xor(csA, 16, 64);
    csA += __shfl_xor(csA, 32, 64);
    csB += __shfl_xor(csB, 16, 64);
    csB += __shfl_xor(csB, 32, 64);

    const float uA = csA * capinv;
    const float uB = csB * capinv;

    // fused stats: group 0 sums u, 1 sums u^2, 2 sums u*cur, 3 maxes u
    float valA = (g == 0) ? uA : (g == 1) ? (uA * uA)
               : (g == 2) ? (uA * cur2[buf][0]) : uA;
    float valB = (g == 0) ? uB : (g == 1) ? (uB * uB)
               : (g == 2) ? (uB * cur2[buf][1]) : uB;
#pragma unroll
    for (int m = 1; m < 16; m <<= 1) {
      const float oA  = __shfl_xor(valA, m, 64);
      const float smA = valA + oA;
      const float mmA = fmaxf(valA, oA);
      valA = (g == 3) ? mmA : smA;
      const float oB  = __shfl_xor(valB, m, 64);
      const float smB = valB + oB;
      const float mmB = fmaxf(valB, oB);
      valB = (g == 3) ? mmB : smB;
    }
    {
      const float s1 = read_lane_f(valA, 0);
      const float s2 = read_lane_f(valA, 16);
      const float s3 = read_lane_f(valA, 32);
      const float mx = read_lane_f(valA, 48);
      const float var = (s2 - s1 * s1 * (1.0f / 16.0f)) * (1.0f / 15.0f); // ddof=1
      acc += 0.3f * var + 0.5f * s3 + 0.2f * mx;
    }
    {
      const float s1 = read_lane_f(valB, 0);
      const float s2 = read_lane_f(valB, 16);
      const float s3 = read_lane_f(valB, 32);
      const float mx = read_lane_f(valB, 48);
      const float var = (s2 - s1 * s1 * (1.0f / 16.0f)) * (1.0f / 15.0f);
      acc += 0.3f * var + 0.5f * s3 + 0.2f * mx;
    }
  }

  if (lane == 0) wacc[w] = acc;
  __syncthreads();
  if (tid == 0) partials[blockIdx.x] = wacc[0] + wacc[1] + wacc[2] + wacc[3];
}

__global__ __launch_bounds__(256) void reduce_kernel(
    const float* __restrict__ partials, int n, float* __restrict__ out, float invB)
{
  __shared__ float s[256];
  const int tid = threadIdx.x;
  const float4* p4 = (const float4*)partials;
  const int n4 = n >> 2;
  float a = 0.0f;
  for (int i = tid; i < n4; i += 256) {
    const float4 v = p4[i];
    a += v.x + v.y + v.z + v.w;
  }
  s[tid] = a;
  __syncthreads();
  for (int st = 128; st > 0; st >>= 1) {
    if (tid < st) s[tid] += s[tid + st];
    __syncthreads();
  }
  if (tid == 0) out[0] = s[0] * invB;
}

extern "C" void kernel_launch(void* const* d_in, const int* in_sizes, int n_in,
                              void* d_out, int out_size, void* d_ws, size_t ws_size,
                              hipStream_t stream) {
  const float* pred    = (const float*)d_in[0];  // [B, T]
  const float* demands = (const float*)d_in[1];  // [B, D]
  const float* cur     = (const float*)d_in[2];  // [B, L]
  const float* caps    = (const float*)d_in[3];  // [L]
  const int*   t2l     = (const int*)d_in[4];    // [T]
  float* out = (float*)d_out;

  const int L = in_sizes[3];          // 16
  const int B = in_sizes[2] / L;      // 16384

  const int grid = GRID_BLOCKS;         // 512, each block handles NITER*8 rows
  float* partials = (float*)d_ws;       // grid floats

  rowloss_kernel<<<grid, 256, 0, stream>>>(pred, demands, cur, caps, t2l, partials);
  reduce_kernel<<<1, 256, 0, stream>>>(partials, grid, out, 1.0f / (float)B);
}